// Round 2
// baseline (207.856 us; speedup 1.0000x reference)
//
#include <hip/hip_runtime.h>

constexpr int BLK = 256;  // threads == elements per block

// Compiler-proof IEEE f32 rn ops (inline asm: no fusion/reassociation
// beyond what is written).
__device__ __forceinline__ float mul_rn(float a, float b) {
    float r; asm("v_mul_f32 %0, %1, %2" : "=v"(r) : "v"(a), "v"(b)); return r;
}
__device__ __forceinline__ float add_rn(float a, float b) {
    float r; asm("v_add_f32 %0, %1, %2" : "=v"(r) : "v"(a), "v"(b)); return r;
}
__device__ __forceinline__ float sub_rn(float a, float b) {
    float r; asm("v_sub_f32 %0, %1, %2" : "=v"(r) : "v"(a), "v"(b)); return r;
}
__device__ __forceinline__ float fma_rn(float a, float b, float c) {
    float r; asm("v_fma_f32 %0, %1, %2, %3"
                 : "=v"(r) : "v"(a), "v"(b), "v"(c)); return r;
}

// Ascending FMA chain from zero — the evaluation shared by an XLA-lowered
// dot loop (acc=0; acc=fma(a_j,b_j,acc)) and BLAS 3x3 microkernels:
//   fma(a2,b2, fma(a1,b1, rn(a0*b0)))      [fma(a0,b0,0) == rn(a0*b0)]
// This chain is what passes the razor elements (1+ca ~ 1e-7). Do not
// reassociate; do not let the compiler contract it differently.
__device__ __forceinline__ float dot3_fma_asc(float a0, float a1, float a2,
                                              float b0, float b1, float b2) {
    return fma_rn(a2, b2, fma_rn(a1, b1, mul_rn(a0, b0)));
}

// Occupancy note: LDS is the block-residency limiter.
//   3 staged arrays: 27648 B -> 5 blocks/CU = 20/32 waves (62.5% cap, meas 45%)
//   2 staged arrays: 18432 B -> 8 blocks/CU = 32/32 waves (100% cap)
// R is read directly per-thread: a wave's 64 lanes cover one contiguous
// 64*36 = 2304 B span, so every fetched cache line is fully consumed.
// __launch_bounds__(256, 8): 8 waves/EU forces VGPR <= 64 so the 9 live R
// values can't push us over the 64-VGPR occupancy step.
__global__ __launch_bounds__(BLK, 8) void so3_nll_kernel(
    const float* __restrict__ C_est,
    const float* __restrict__ C_tgt,
    const float* __restrict__ Rinv,
    float* __restrict__ out,
    int B)
{
    __shared__ float sE[BLK * 9];
    __shared__ float sT[BLK * 9];

    const int tid  = threadIdx.x;
    const int b0   = blockIdx.x * BLK;
    const int nrem = min(BLK, B - b0);   // elements handled by this block
    const int nflt = nrem * 9;           // floats per staged input array
    const int nvec = nflt >> 2;          // full float4 chunks

    // Coalesced global -> LDS staging for E, T. Block base byte offset =
    // b0*36, b0 multiple of 256 -> offset multiple of 9216 (16B aligned).
    const float4* gE = reinterpret_cast<const float4*>(C_est + (size_t)b0 * 9);
    const float4* gT = reinterpret_cast<const float4*>(C_tgt + (size_t)b0 * 9);

    for (int i = tid; i < nvec; i += BLK) {
        float4 e = gE[i];
        float4 t = gT[i];
        *reinterpret_cast<float4*>(&sE[i * 4]) = e;
        *reinterpret_cast<float4*>(&sT[i * 4]) = t;
    }
    // Scalar tail (nflt % 4 floats) — only possible in the last block.
    for (int i = (nvec << 2) + tid; i < nflt; i += BLK) {
        sE[i] = C_est[(size_t)b0 * 9 + i];
        sT[i] = C_tgt[(size_t)b0 * 9 + i];
    }

    // R: direct per-thread loads, issued BEFORE the barrier so their
    // latency hides under the staging drain + dot-product phase.
    float R0 = 0.f, R1 = 0.f, R2 = 0.f, R3 = 0.f, R4 = 0.f,
          R5 = 0.f, R6 = 0.f, R7 = 0.f, R8 = 0.f;
    if (tid < nrem) {
        const float* Rp = Rinv + (size_t)(b0 + tid) * 9;
        R0 = Rp[0]; R1 = Rp[1]; R2 = Rp[2];
        R3 = Rp[3]; R4 = Rp[4]; R5 = Rp[5];
        R6 = Rp[6]; R7 = Rp[7]; R8 = Rp[8];
    }

    __syncthreads();

    if (tid < nrem) {
        const float* E = &sE[tid * 9];   // stride 9 (odd) -> 2-way max = free
        const float* T = &sT[tid * 9];

        // ---- chaotic chain: must match the np ref's f32 rounding ----
        float d00 = dot3_fma_asc(E[0],E[1],E[2], T[0],T[1],T[2]);
        float d11 = dot3_fma_asc(E[3],E[4],E[5], T[3],T[4],T[5]);
        float d22 = dot3_fma_asc(E[6],E[7],E[8], T[6],T[7],T[8]);

        float tr = add_rn(add_rn(d00, d11), d22);    // (d00+d11)+d22
        float ca = 0.5f * sub_rn(tr, 1.0f);          // *0.5 exact
        constexpr float HI = 1.0f - 1e-7f;           // 0x3F7FFFFE == np bound
        ca = fminf(fmaxf(ca, -HI), HI);
        float angle = acosf(ca);
        float sa    = sinf(angle);
        // clamp => angle >= ~4.9e-4 > 1e-6: reference Taylor branch is dead
        float coef = (0.5f * angle) / sa;

        // ---- vee path: same chain for consistency ----
        float d01 = dot3_fma_asc(E[0],E[1],E[2], T[3],T[4],T[5]);
        float d02 = dot3_fma_asc(E[0],E[1],E[2], T[6],T[7],T[8]);
        float d10 = dot3_fma_asc(E[3],E[4],E[5], T[0],T[1],T[2]);
        float d12 = dot3_fma_asc(E[3],E[4],E[5], T[6],T[7],T[8]);
        float d20 = dot3_fma_asc(E[6],E[7],E[8], T[0],T[1],T[2]);
        float d21 = dot3_fma_asc(E[6],E[7],E[8], T[3],T[4],T[5]);

        float r0 = coef * sub_rn(d21, d12);
        float r1 = coef * sub_rn(d02, d20);
        float r2 = coef * sub_rn(d10, d01);

        // ---- well-conditioned tail: plain f32 ----
        float w = 0.5f * (r0 * ((R0*r0 + R1*r1) + R2*r2) +
                          r1 * ((R3*r0 + R4*r1) + R5*r2) +
                          r2 * ((R6*r0 + R7*r1) + R8*r2));

        float det = R0 * (R4*R8 - R5*R7)
                  - R1 * (R3*R8 - R5*R6)
                  + R2 * (R3*R7 - R4*R6);

        out[b0 + tid] = w - 0.5f * logf(det);
    }
}

extern "C" void kernel_launch(void* const* d_in, const int* in_sizes, int n_in,
                              void* d_out, int out_size, void* d_ws, size_t ws_size,
                              hipStream_t stream) {
    const float* C_est = (const float*)d_in[0];
    const float* C_tgt = (const float*)d_in[1];
    const float* Rinv  = (const float*)d_in[2];
    float* out = (float*)d_out;

    const int B = in_sizes[0] / 9;
    const int blocks = (B + BLK - 1) / BLK;
    so3_nll_kernel<<<blocks, BLK, 0, stream>>>(C_est, C_tgt, Rinv, out, B);
}

// Round 3
// 207.691 us; speedup vs baseline: 1.0008x; 1.0008x over previous
//
#include <hip/hip_runtime.h>

constexpr int BLK = 256;        // threads == elements per chunk
constexpr int GRID_CAP = 1024;  // 4 blocks/CU on 256 CUs (LDS-limited residency)

// Compiler-proof IEEE f32 rn ops (inline asm: no fusion/reassociation
// beyond what is written).
__device__ __forceinline__ float mul_rn(float a, float b) {
    float r; asm("v_mul_f32 %0, %1, %2" : "=v"(r) : "v"(a), "v"(b)); return r;
}
__device__ __forceinline__ float add_rn(float a, float b) {
    float r; asm("v_add_f32 %0, %1, %2" : "=v"(r) : "v"(a), "v"(b)); return r;
}
__device__ __forceinline__ float sub_rn(float a, float b) {
    float r; asm("v_sub_f32 %0, %1, %2" : "=v"(r) : "v"(a), "v"(b)); return r;
}
__device__ __forceinline__ float fma_rn(float a, float b, float c) {
    float r; asm("v_fma_f32 %0, %1, %2, %3"
                 : "=v"(r) : "v"(a), "v"(b), "v"(c)); return r;
}

// Ascending FMA chain from zero — matches the np/XLA-lowered dot rounding:
//   fma(a2,b2, fma(a1,b1, rn(a0*b0)))
// Do not reassociate; do not let the compiler contract it differently.
__device__ __forceinline__ float dot3_fma_asc(float a0, float a1, float a2,
                                              float b0, float b1, float b2) {
    return fma_rn(a2, b2, fma_rn(a1, b1, mul_rn(a0, b0)));
}

// Persistent double-buffered pipeline. Evidence-driven rationale (R0/R2):
//  - occupancy 45% vs 70% gave IDENTICAL 79 us => residency is not the lever;
//  - an L3-resident dispatch also took 79 us => not HBM-bound;
//  - VALUBusy 11%, conflicts 0 => the limiter is the per-block serial chain
//    {staging latency -> barrier -> compute}, repeated 30x per CU.
// Fix: each block loops over ~7.6 chunks; while computing chunk k from LDS
// buffer `cur`, the global loads for chunk k+1 are already in flight
// (issued BEFORE compute, AFTER the R loads so vmcnt FIFO lets compute wait
// only on R). ds_write of k+1 lands after compute; one barrier per chunk.
__global__ __launch_bounds__(BLK, 4) void so3_nll_kernel(
    const float* __restrict__ C_est,
    const float* __restrict__ C_tgt,
    const float* __restrict__ Rinv,
    float* __restrict__ out,
    int B)
{
    __shared__ float sE[2][BLK * 9];
    __shared__ float sT[2][BLK * 9];

    const int tid     = threadIdx.x;
    const int nchunks = (B + BLK - 1) / BLK;
    const int G       = gridDim.x;

    int c = blockIdx.x;
    if (c >= nchunks) return;   // block-uniform: safe w.r.t. barriers

    // ---- prologue: stage chunk c into buffer 0 (register roundtrip) ----
    {
        const int b0   = c * BLK;
        const int nflt = min(BLK, B - b0) * 9;
        const int nvec = nflt >> 2;
        const float4* gE = reinterpret_cast<const float4*>(C_est + (size_t)b0 * 9);
        const float4* gT = reinterpret_cast<const float4*>(C_tgt + (size_t)b0 * 9);
        for (int i = tid; i < nvec; i += BLK) {
            float4 e = gE[i];
            float4 t = gT[i];
            *reinterpret_cast<float4*>(&sE[0][i * 4]) = e;
            *reinterpret_cast<float4*>(&sT[0][i * 4]) = t;
        }
        for (int i = (nvec << 2) + tid; i < nflt; i += BLK) {
            sE[0][i] = C_est[(size_t)b0 * 9 + i];
            sT[0][i] = C_tgt[(size_t)b0 * 9 + i];
        }
    }
    __syncthreads();

    int cur = 0;
    for (; c < nchunks; c += G) {
        const int b0   = c * BLK;
        const int nrem = min(BLK, B - b0);

        // ---- R loads for CURRENT chunk: issue FIRST (oldest in vmcnt FIFO)
        // so compute's wait on R leaves the younger staging loads in flight.
        // Index clamp instead of predication: OOB lanes load a valid dup.
        const float* Rp = Rinv + (size_t)(b0 + min(tid, nrem - 1)) * 9;
        float R0 = Rp[0], R1 = Rp[1], R2 = Rp[2];
        float R3 = Rp[3], R4 = Rp[4], R5 = Rp[5];
        float R6 = Rp[6], R7 = Rp[7], R8 = Rp[8];

        // ---- staging loads for NEXT chunk: issue now, consume after compute.
        const int  cn       = c + G;
        const bool has_next = (cn < nchunks);
        float4 eA, eB, eC, tA, tB, tC;
        float  scE = 0.f, scT = 0.f;
        int    nvecN = 0, nfltN = 0, tiN = 0;
        if (has_next) {
            const int b0n = cn * BLK;
            nfltN = min(BLK, B - b0n) * 9;
            nvecN = nfltN >> 2;
            const float4* gEn = reinterpret_cast<const float4*>(C_est + (size_t)b0n * 9);
            const float4* gTn = reinterpret_cast<const float4*>(C_tgt + (size_t)b0n * 9);
            // clamp: duplicate loads for OOB lanes (writes also clamp => benign)
            const int iA = min(tid,           nvecN - 1);
            const int iB = min(tid + BLK,     nvecN - 1);
            const int iC = min(tid + 2 * BLK, nvecN - 1);
            eA = gEn[iA]; tA = gTn[iA];
            eB = gEn[iB]; tB = gTn[iB];
            eC = gEn[iC]; tC = gTn[iC];
            // scalar tail floats (nfltN % 4, at most 3 lanes; none when B=2M)
            tiN = (nvecN << 2) + tid;
            if (tiN < nfltN) {
                scE = C_est[(size_t)b0n * 9 + tiN];
                scT = C_tgt[(size_t)b0n * 9 + tiN];
            }
        }

        // ---- compute CURRENT chunk from LDS[cur] + R regs ----
        if (tid < nrem) {
            const float* E = &sE[cur][tid * 9];  // stride 9 (odd): 2-way = free
            const float* T = &sT[cur][tid * 9];

            // chaotic chain: must match the np ref's f32 rounding
            float d00 = dot3_fma_asc(E[0],E[1],E[2], T[0],T[1],T[2]);
            float d11 = dot3_fma_asc(E[3],E[4],E[5], T[3],T[4],T[5]);
            float d22 = dot3_fma_asc(E[6],E[7],E[8], T[6],T[7],T[8]);

            float tr = add_rn(add_rn(d00, d11), d22);   // (d00+d11)+d22
            float ca = 0.5f * sub_rn(tr, 1.0f);         // *0.5 exact
            constexpr float HI = 1.0f - 1e-7f;          // 0x3F7FFFFE == np bound
            ca = fminf(fmaxf(ca, -HI), HI);
            float angle = acosf(ca);
            float sa    = sinf(angle);
            // clamp => angle >= ~4.9e-4 > 1e-6: reference Taylor branch is dead
            float coef = (0.5f * angle) / sa;

            // vee path: same chain for consistency
            float d01 = dot3_fma_asc(E[0],E[1],E[2], T[3],T[4],T[5]);
            float d02 = dot3_fma_asc(E[0],E[1],E[2], T[6],T[7],T[8]);
            float d10 = dot3_fma_asc(E[3],E[4],E[5], T[0],T[1],T[2]);
            float d12 = dot3_fma_asc(E[3],E[4],E[5], T[6],T[7],T[8]);
            float d20 = dot3_fma_asc(E[6],E[7],E[8], T[0],T[1],T[2]);
            float d21 = dot3_fma_asc(E[6],E[7],E[8], T[3],T[4],T[5]);

            float r0 = coef * sub_rn(d21, d12);
            float r1 = coef * sub_rn(d02, d20);
            float r2 = coef * sub_rn(d10, d01);

            // well-conditioned tail: plain f32
            float w = 0.5f * (r0 * ((R0*r0 + R1*r1) + R2*r2) +
                              r1 * ((R3*r0 + R4*r1) + R5*r2) +
                              r2 * ((R6*r0 + R7*r1) + R8*r2));

            float det = R0 * (R4*R8 - R5*R7)
                      - R1 * (R3*R8 - R5*R6)
                      + R2 * (R3*R7 - R4*R6);

            out[b0 + tid] = w - 0.5f * logf(det);
        }

        // ---- write NEXT chunk into the other buffer (loads have landed
        // behind the compute); clamped lanes rewrite the same value => benign.
        if (has_next) {
            float* dE = sE[cur ^ 1];
            float* dT = sT[cur ^ 1];
            const int iA = min(tid,           nvecN - 1);
            const int iB = min(tid + BLK,     nvecN - 1);
            const int iC = min(tid + 2 * BLK, nvecN - 1);
            *reinterpret_cast<float4*>(&dE[iA * 4]) = eA;
            *reinterpret_cast<float4*>(&dT[iA * 4]) = tA;
            *reinterpret_cast<float4*>(&dE[iB * 4]) = eB;
            *reinterpret_cast<float4*>(&dT[iB * 4]) = tB;
            *reinterpret_cast<float4*>(&dE[iC * 4]) = eC;
            *reinterpret_cast<float4*>(&dT[iC * 4]) = tC;
            if (tiN < nfltN) { dE[tiN] = scE; dT[tiN] = scT; }
        }

        // Single barrier per chunk: separates this iteration's reads of
        // buf[cur] + writes of buf[cur^1] from the next iteration's
        // reads of buf[cur^1] + writes of buf[cur]. Both hazards covered.
        __syncthreads();
        cur ^= 1;
    }
}

extern "C" void kernel_launch(void* const* d_in, const int* in_sizes, int n_in,
                              void* d_out, int out_size, void* d_ws, size_t ws_size,
                              hipStream_t stream) {
    const float* C_est = (const float*)d_in[0];
    const float* C_tgt = (const float*)d_in[1];
    const float* Rinv  = (const float*)d_in[2];
    float* out = (float*)d_out;

    const int B = in_sizes[0] / 9;
    const int nchunks = (B + BLK - 1) / BLK;
    const int blocks = nchunks < GRID_CAP ? nchunks : GRID_CAP;
    so3_nll_kernel<<<blocks, BLK, 0, stream>>>(C_est, C_tgt, Rinv, out, B);
}

// Round 5
// 206.533 us; speedup vs baseline: 1.0064x; 1.0056x over previous
//
#include <hip/hip_runtime.h>

constexpr int BLK = 256;

// Compiler-proof IEEE f32 rn ops (inline asm: no fusion/reassociation
// beyond what is written).
__device__ __forceinline__ float mul_rn(float a, float b) {
    float r; asm("v_mul_f32 %0, %1, %2" : "=v"(r) : "v"(a), "v"(b)); return r;
}
__device__ __forceinline__ float add_rn(float a, float b) {
    float r; asm("v_add_f32 %0, %1, %2" : "=v"(r) : "v"(a), "v"(b)); return r;
}
__device__ __forceinline__ float sub_rn(float a, float b) {
    float r; asm("v_sub_f32 %0, %1, %2" : "=v"(r) : "v"(a), "v"(b)); return r;
}
__device__ __forceinline__ float fma_rn(float a, float b, float c) {
    float r; asm("v_fma_f32 %0, %1, %2, %3"
                 : "=v"(r) : "v"(a), "v"(b), "v"(c)); return r;
}

// Ascending FMA chain from zero — matches the np/XLA-lowered dot rounding:
//   fma(a2,b2, fma(a1,b1, rn(a0*b0)))
// Do not reassociate; do not let the compiler contract it differently.
__device__ __forceinline__ float dot3_fma_asc(float a0, float a1, float a2,
                                              float b0, float b1, float b2) {
    return fma_rn(a2, b2, fma_rn(a1, b1, mul_rn(a0, b0)));
}

// Per-thread direct load of 9 contiguous floats (36 B) at arbitrary 4-B
// alignment: two unaligned 16-B loads + one scalar. gfx950 global loads
// only need dword alignment, so clang emits global_load_dwordx4 freely.
// Across a wave, lanes cover one contiguous 64*36 = 2304 B span: every
// byte of every fetched cache line is consumed -> zero over-fetch.
__device__ __forceinline__ void load9(const float* __restrict__ p, float* d) {
    float4 a, b;
    __builtin_memcpy(&a, p,     16);
    __builtin_memcpy(&b, p + 4, 16);
    float c = p[8];
    d[0] = a.x; d[1] = a.y; d[2] = a.z; d[3] = a.w;
    d[4] = b.x; d[5] = b.y; d[6] = b.z; d[7] = b.w;
    d[8] = c;
}

// Round-4 discriminating experiment: NO LDS, NO barrier, NO staging.
// Evidence (R0/R2/R3): 80 us/dispatch is invariant to occupancy (35-70%),
// data source (HBM vs L3-resident), and software pipelining — every tested
// variant shared the global->LDS->barrier staging structure. This kernel
// deletes that structure: pure elementwise, 1 thread = 1 element, direct
// loads, dependent only on its own 9 VMEM instructions.
__global__ __launch_bounds__(BLK, 8) void so3_nll_kernel(
    const float* __restrict__ C_est,
    const float* __restrict__ C_tgt,
    const float* __restrict__ Rinv,
    float* __restrict__ out,
    int B)
{
    const int i_raw = blockIdx.x * BLK + threadIdx.x;
    const int i     = min(i_raw, B - 1);     // clamp: loads always in-bounds
    const size_t base = (size_t)i * 9;

    float E[9], T[9], R[9];
    load9(C_est + base, E);
    load9(C_tgt + base, T);
    load9(Rinv  + base, R);

    // ---- chaotic chain: must match the np ref's f32 rounding ----
    float d00 = dot3_fma_asc(E[0],E[1],E[2], T[0],T[1],T[2]);
    float d11 = dot3_fma_asc(E[3],E[4],E[5], T[3],T[4],T[5]);
    float d22 = dot3_fma_asc(E[6],E[7],E[8], T[6],T[7],T[8]);

    float tr = add_rn(add_rn(d00, d11), d22);    // (d00+d11)+d22
    float ca = 0.5f * sub_rn(tr, 1.0f);          // *0.5 exact
    constexpr float HI = 1.0f - 1e-7f;           // 0x3F7FFFFE == np bound
    ca = fminf(fmaxf(ca, -HI), HI);
    float angle = acosf(ca);
    float sa    = sinf(angle);
    // clamp => angle >= ~4.9e-4 > 1e-6: reference Taylor branch is dead
    float coef = (0.5f * angle) / sa;

    // ---- vee path: same chain for consistency ----
    float d01 = dot3_fma_asc(E[0],E[1],E[2], T[3],T[4],T[5]);
    float d02 = dot3_fma_asc(E[0],E[1],E[2], T[6],T[7],T[8]);
    float d10 = dot3_fma_asc(E[3],E[4],E[5], T[0],T[1],T[2]);
    float d12 = dot3_fma_asc(E[3],E[4],E[5], T[6],T[7],T[8]);
    float d20 = dot3_fma_asc(E[6],E[7],E[8], T[0],T[1],T[2]);
    float d21 = dot3_fma_asc(E[6],E[7],E[8], T[3],T[4],T[5]);

    float r0 = coef * sub_rn(d21, d12);
    float r1 = coef * sub_rn(d02, d20);
    float r2 = coef * sub_rn(d10, d01);

    // ---- well-conditioned tail: plain f32 ----
    float w = 0.5f * (r0 * ((R[0]*r0 + R[1]*r1) + R[2]*r2) +
                      r1 * ((R[3]*r0 + R[4]*r1) + R[5]*r2) +
                      r2 * ((R[6]*r0 + R[7]*r1) + R[8]*r2));

    float det = R[0] * (R[4]*R[8] - R[5]*R[7])
              - R[1] * (R[3]*R[8] - R[5]*R[6])
              + R[2] * (R[3]*R[7] - R[4]*R[6]);

    if (i_raw < B)
        out[i_raw] = w - 0.5f * logf(det);
}

extern "C" void kernel_launch(void* const* d_in, const int* in_sizes, int n_in,
                              void* d_out, int out_size, void* d_ws, size_t ws_size,
                              hipStream_t stream) {
    const float* C_est = (const float*)d_in[0];
    const float* C_tgt = (const float*)d_in[1];
    const float* Rinv  = (const float*)d_in[2];
    float* out = (float*)d_out;

    const int B = in_sizes[0] / 9;
    const int blocks = (B + BLK - 1) / BLK;
    so3_nll_kernel<<<blocks, BLK, 0, stream>>>(C_est, C_tgt, Rinv, out, B);
}